// Round 1
// baseline (411.894 us; speedup 1.0000x reference)
//
#include <hip/hip_runtime.h>

#define NCLS 80
#define NMK  32
#define NB   8400
#define MH_  160
#define MP   25600     // 160*160
#define IH   640
#define IW   640
#define KTOP 100
#define CONFT 0.4f
#define IOUT 0.7f
#define CHUNK 3072

// ---------------- k_prep: score / argmax / sort key, rank init ----------------
__global__ __launch_bounds__(256) void k_prep(const float* __restrict__ det,
    float* __restrict__ score, float* __restrict__ key,
    int* __restrict__ cid, int* __restrict__ rank)
{
  int n = blockIdx.x*256 + threadIdx.x;
  if (n >= NB) return;
  float best = det[4*NB + n];
  int bc = 0;
  #pragma unroll 8
  for (int c = 1; c < NCLS; ++c){
    float v = det[(4+c)*NB + n];
    if (v > best){ best = v; bc = c; }   // strict > keeps FIRST max (matches jnp.argmax)
  }
  score[n] = best;
  cid[n] = bc;
  key[n] = (best >= CONFT) ? -best : __builtin_inff();  // argsort key (ascending)
  rank[n] = 0;
}

// ---------------- k_rank: O(N^2) stable rank, j-sliced 8 ways ----------------
__global__ __launch_bounds__(256) void k_rank(const float* __restrict__ key, int* __restrict__ rank)
{
  __shared__ float tk[256];
  int n = blockIdx.x*256 + threadIdx.x;
  float kn = (n < NB) ? key[n] : 0.f;
  int j0 = blockIdx.y * 1050;          // 8 * 1050 == 8400
  int j1 = j0 + 1050;
  int part = 0;
  for (int t0 = j0; t0 < j1; t0 += 256){
    int j = t0 + threadIdx.x;
    tk[threadIdx.x] = (j < NB) ? key[j] : 0.f;
    __syncthreads();
    int lim = min(256, j1 - t0);
    for (int jj = 0; jj < lim; ++jj){
      float kj = tk[jj];
      int jg = t0 + jj;
      part += ((kj < kn) || (kj == kn && jg < n)) ? 1 : 0;  // stable: ties by index
    }
    __syncthreads();
  }
  if (n < NB && part) atomicAdd(&rank[n], part);
}

// ---------------- k_scatter: build sorted arrays ----------------
__global__ __launch_bounds__(256) void k_scatter(const float* __restrict__ det,
    const float* __restrict__ key, const int* __restrict__ cid, const int* __restrict__ rank,
    int* __restrict__ perm, float* __restrict__ skey, int* __restrict__ scid, float4* __restrict__ sbox)
{
  int n = blockIdx.x*256 + threadIdx.x;
  if (n >= NB) return;
  int r = rank[n];
  perm[r] = n;
  skey[r] = key[n];
  scid[r] = cid[n];
  float4 b;
  b.x = det[0*NB + n]; b.y = det[1*NB + n];
  b.z = det[2*NB + n]; b.w = det[3*NB + n];
  sbox[r] = b;
}

// ---------------- k_nms: single-block chunked greedy NMS, stop at 100 kept ----------------
__global__ __launch_bounds__(512) void k_nms(const float4* __restrict__ sbox,
    const float* __restrict__ skey, const int* __restrict__ scid, const int* __restrict__ perm,
    int* __restrict__ selorig, int4* __restrict__ selbox, int* __restrict__ selcid, int* __restrict__ nsel)
{
  __shared__ float4 cb[CHUNK];
  __shared__ unsigned long long keepm[CHUNK/64];
  __shared__ float4 keptbox[KTOP];
  __shared__ int keptidx[KTOP];
  __shared__ int s_found;
  __shared__ int s_next;
  const int tid  = threadIdx.x;
  const int lane = tid & 63;
  const int wv   = tid >> 6;     // 8 waves
  if (tid == 0) s_found = 0;
  __syncthreads();

  for (int c0 = 0; c0 < NB; c0 += CHUNK){
    if (s_found >= KTOP) break;                  // uniform (LDS, post-barrier)
    const int n  = min(CHUNK, NB - c0);
    const int nw = (n + 63) >> 6;
    // load chunk boxes + init keep bits (valid prefix: key < inf)
    for (int jb = wv*64; jb < nw*64; jb += 512){
      int j = jb + lane;
      bool valid = false;
      if (j < n){
        cb[j] = sbox[c0 + j];
        valid = skey[c0 + j] < 1e38f;
      }
      unsigned long long bal = __ballot(valid);
      if (lane == 0) keepm[jb >> 6] = bal;
    }
    __syncthreads();
    // suppress by boxes kept in previous chunks
    {
      int fnd = s_found;
      for (int ki = 0; ki < fnd; ++ki){
        float4 kb = keptbox[ki];
        float ka = (kb.z - kb.x) * (kb.w - kb.y);
        for (int jb = wv*64; jb < nw*64; jb += 512){
          int j = jb + lane;
          bool sup = false;
          if (j < n){
            float4 bj = cb[j];
            float ix1 = fmaxf(kb.x, bj.x), iy1 = fmaxf(kb.y, bj.y);
            float ix2 = fminf(kb.z, bj.z), iy2 = fminf(kb.w, bj.w);
            float inter = fmaxf(ix2 - ix1, 0.f) * fmaxf(iy2 - iy1, 0.f);
            float aj = (bj.z - bj.x) * (bj.w - bj.y);
            sup = inter / (ka + aj - inter) >= IOUT;
          }
          unsigned long long bal = __ballot(sup);
          if (lane == 0) keepm[jb >> 6] &= ~bal;
        }
      }
    }
    __syncthreads();
    // greedy within chunk
    int i = 0;
    for (;;){
      if (tid < 64){  // wave0: parallel scan for next set bit >= i
        unsigned long long wbits = (tid < nw) ? keepm[tid] : 0ull;
        int base = tid << 6;
        if (base + 64 <= i) wbits = 0ull;
        else if (base < i)  wbits &= (~0ull) << (i - base);
        int pos = wbits ? (base + __builtin_ctzll(wbits)) : 0x7fffffff;
        #pragma unroll
        for (int s = 32; s > 0; s >>= 1) pos = min(pos, __shfl_xor(pos, s, 64));
        if (tid == 0) s_next = pos;
      }
      __syncthreads();
      i = s_next;
      if (i >= n) break;
      float4 bi = cb[i];
      if (tid == 0){
        keptbox[s_found] = bi;
        keptidx[s_found] = c0 + i;
        s_found = s_found + 1;
      }
      __syncthreads();
      if (s_found >= KTOP) break;       // 100th kept never needs to suppress
      float ai = (bi.z - bi.x) * (bi.w - bi.y);
      int start = i & ~63;
      for (int jb = start + wv*64; jb < nw*64; jb += 512){
        int j = jb + lane;
        bool sup = false;
        if (j < n && j > i){
          float4 bj = cb[j];
          float ix1 = fmaxf(bi.x, bj.x), iy1 = fmaxf(bi.y, bj.y);
          float ix2 = fminf(bi.z, bj.z), iy2 = fminf(bi.w, bj.w);
          float inter = fmaxf(ix2 - ix1, 0.f) * fmaxf(iy2 - iy1, 0.f);
          float aj = (bj.z - bj.x) * (bj.w - bj.y);
          sup = inter / (ai + aj - inter) >= IOUT;   // exact reference fp32 expression
        }
        unsigned long long bal = __ballot(sup);
        if (lane == 0) keepm[jb >> 6] &= ~bal;
      }
      __syncthreads();
      i = i + 1;
    }
    __syncthreads();
  }
  __syncthreads();
  int fnd = s_found;
  if (tid < fnd){
    int si = keptidx[tid];
    float4 b = keptbox[tid];
    selorig[tid] = perm[si];
    selbox[tid]  = make_int4((int)b.x, (int)b.y, (int)b.z, (int)b.w);  // trunc == floor (coords >= 0)
    selcid[tid]  = scid[si];
  }
  if (tid == 0) *nsel = fnd;
}

// ---------------- k_mask: mask logits (32-dot) -> hard bits ----------------
__global__ __launch_bounds__(256) void k_mask(const float* __restrict__ det, const float* __restrict__ proto,
    const int* __restrict__ selorig, const int* __restrict__ nsel, unsigned int* __restrict__ hb)
{
  const int p    = blockIdx.x*256 + threadIdx.x;          // 0..25599
  const int lane = threadIdx.x & 63;
  const int wword = (blockIdx.x*256 + (threadIdx.x & ~63)) >> 5;  // 2 u32 words per wave
  float pr[NMK];
  #pragma unroll
  for (int m = 0; m < NMK; ++m) pr[m] = proto[m*MP + p];
  const int ns = *nsel;
  const int k0 = blockIdx.y * 10;
  for (int kk = 0; kk < 10; ++kk){
    int k = k0 + kk;
    if (k >= ns) break;                                   // uniform
    int so = selorig[k];
    const float* cf = det + 84*NB + so;                   // uniform -> scalar loads
    float acc = 0.f;
    #pragma unroll
    for (int m = 0; m < NMK; ++m) acc = fmaf(cf[(size_t)m*NB], pr[m], acc);
    unsigned long long bal = __ballot(acc > 0.f);         // hard = sigmoid>0.5 <=> logit>0
    if (lane == 0)  hb[k*800 + wword]     = (unsigned int)bal;
    if (lane == 32) hb[k*800 + wword + 1] = (unsigned int)(bal >> 32);
  }
}

// ---------------- k_paint: winner-per-pixel + coalesced one-hot row writes ----------------
__global__ __launch_bounds__(256) void k_paint(const int4* __restrict__ selbox, const int* __restrict__ selcid,
    const int* __restrict__ nsel, const unsigned int* __restrict__ hb, float* __restrict__ out)
{
  __shared__ int4  sbx[KTOP];
  __shared__ int   scd[KTOP];
  __shared__ short wcls[IW];
  __shared__ short clist[KTOP];
  __shared__ int   ccount;
  const int y = blockIdx.x;
  const int tid = threadIdx.x;
  const int ns = *nsel;
  if (tid < ns){ sbx[tid] = selbox[tid]; scd[tid] = selcid[tid]; }
  if (tid == 0) ccount = 0;
  __syncthreads();
  if (tid == 0){  // boxes intersecting this row, ascending k
    int m = 0;
    for (int k = 0; k < ns; ++k)
      if (y >= sbx[k].y && y < sbx[k].w) clist[m++] = (short)k;
    ccount = m;
  }
  __syncthreads();
  const int m = ccount;
  const int fyi = (y - 2) >> 2;                      // floor((y+0.5)/4 - 0.5)
  const int ylo = max(fyi, 0), yhi = min(fyi + 1, MH_ - 1);
  for (int x = tid; x < IW; x += 256){
    int cls = -1;
    for (int ci = m - 1; ci >= 0; --ci){             // highest k containing pixel wins
      int k = clist[ci];
      int4 b = sbx[k];
      if (x >= b.x && x < b.z){
        int fx = (x - 2) >> 2;
        int xlo = max(fx, 0), xhi = min(fx + 1, MH_ - 1);
        bool on = false;
        for (int ry = ylo; ry <= yhi; ++ry)
          for (int rx = xlo; rx <= xhi; ++rx){
            int pp = ry*MH_ + rx;
            on = on || ((hb[k*800 + (pp >> 5)] >> (pp & 31)) & 1u);
          }
        cls = on ? scd[k] : -1;                      // painted-zero == untouched-zero
        break;
      }
    }
    wcls[x] = (short)cls;
  }
  __syncthreads();
  // write 640*80 floats for this row, float4-coalesced (80 % 4 == 0 -> no pixel crossing)
  float4* o4 = (float4*)(out + (size_t)y * (IW*NCLS));
  for (int it = 0; it < 50; ++it){
    int f4 = it*256 + tid;         // 0..12799
    int x  = f4 / 20;
    int c  = (f4 % 20) * 4;
    int wc = wcls[x];
    float4 v;
    v.x = (wc == c    ) ? 1.f : 0.f;
    v.y = (wc == c + 1) ? 1.f : 0.f;
    v.z = (wc == c + 2) ? 1.f : 0.f;
    v.w = (wc == c + 3) ? 1.f : 0.f;
    o4[f4] = v;
  }
}

extern "C" void kernel_launch(void* const* d_in, const int* in_sizes, int n_in,
                              void* d_out, int out_size, void* d_ws, size_t ws_size,
                              hipStream_t stream)
{
  const float* det   = (const float*)d_in[0];   // (1,116,8400)
  const float* proto = (const float*)d_in[1];   // (1,32,160,160)
  float* out = (float*)d_out;                   // (1,640,640,80)
  char* w = (char*)d_ws;
  float*  score   = (float*)(w + 0);
  float*  key     = (float*)(w + 33600);
  int*    cid     = (int*)  (w + 67200);
  int*    rank    = (int*)  (w + 100800);
  int*    perm    = (int*)  (w + 134400);
  float*  skey    = (float*)(w + 168000);
  int*    scid    = (int*)  (w + 201600);
  float4* sbox    = (float4*)(w + 235200);      // 16B aligned
  int*    selorig = (int*)  (w + 369600);
  int4*   selbox  = (int4*) (w + 370112);       // 16B aligned
  int*    selcid  = (int*)  (w + 372160);
  int*    nsel    = (int*)  (w + 372672);
  unsigned int* hb = (unsigned int*)(w + 372736);  // 320000 B

  hipLaunchKernelGGL(k_prep,    dim3(33),      dim3(256), 0, stream, det, score, key, cid, rank);
  hipLaunchKernelGGL(k_rank,    dim3(33, 8),   dim3(256), 0, stream, key, rank);
  hipLaunchKernelGGL(k_scatter, dim3(33),      dim3(256), 0, stream, det, key, cid, rank, perm, skey, scid, sbox);
  hipLaunchKernelGGL(k_nms,     dim3(1),       dim3(512), 0, stream, sbox, skey, scid, perm, selorig, selbox, selcid, nsel);
  hipLaunchKernelGGL(k_mask,    dim3(100, 10), dim3(256), 0, stream, det, proto, selorig, nsel, hb);
  hipLaunchKernelGGL(k_paint,   dim3(640),     dim3(256), 0, stream, selbox, selcid, nsel, hb, out);
}

// Round 2
// 293.704 us; speedup vs baseline: 1.4024x; 1.4024x over previous
//
#include <hip/hip_runtime.h>

#define NCLS 80
#define NMK  32
#define NB   8400
#define MH_  160
#define MP   25600     // 160*160
#define IH   640
#define IW   640
#define KTOP 100
#define CONFT 0.4f
#define IOUT 0.7f
#define T_PRE 1024     // NMS prefix handled by bit-matrix
#define TW   (T_PRE/64)  // 16 u64 words per row

// ---------------- k_prep: score/argmax/key + nvalid count ----------------
__global__ __launch_bounds__(256) void k_prep(const float* __restrict__ det,
    float* __restrict__ key, int* __restrict__ cid, int* __restrict__ rank,
    int* __restrict__ nvalid)
{
  int n = blockIdx.x*256 + threadIdx.x;
  if (n >= NB) return;
  float best = det[4*NB + n];
  int bc = 0;
  #pragma unroll 8
  for (int c = 1; c < NCLS; ++c){
    float v = det[(4+c)*NB + n];
    if (v > best){ best = v; bc = c; }   // strict > keeps FIRST max (matches jnp.argmax)
  }
  cid[n] = bc;
  bool valid = best >= CONFT;
  key[n] = valid ? -best : __builtin_inff();  // ascending argsort key; inf sorts last
  rank[n] = 0;
  unsigned long long bal = __ballot(valid);
  if ((threadIdx.x & 63) == 0) atomicAdd(nvalid, (int)__popcll(bal));
}

// ---------------- k_rank: O(N^2) stable rank, j-sliced 8 ways ----------------
__global__ __launch_bounds__(256) void k_rank(const float* __restrict__ key, int* __restrict__ rank)
{
  __shared__ float tk[256];
  int n = blockIdx.x*256 + threadIdx.x;
  float kn = (n < NB) ? key[n] : 0.f;
  int j0 = blockIdx.y * 1050;          // 8 * 1050 == 8400
  int j1 = j0 + 1050;
  int part = 0;
  for (int t0 = j0; t0 < j1; t0 += 256){
    int j = t0 + threadIdx.x;
    tk[threadIdx.x] = (j < NB) ? key[j] : 0.f;
    __syncthreads();
    int lim = min(256, j1 - t0);
    for (int jj = 0; jj < lim; ++jj){
      float kj = tk[jj];
      int jg = t0 + jj;
      part += ((kj < kn) || (kj == kn && jg < n)) ? 1 : 0;  // stable: ties by index
    }
    __syncthreads();
  }
  if (n < NB && part) atomicAdd(&rank[n], part);
}

// ---------------- k_scatter: build sorted arrays ----------------
__global__ __launch_bounds__(256) void k_scatter(const float* __restrict__ det,
    const int* __restrict__ cid, const int* __restrict__ rank,
    int* __restrict__ perm, int* __restrict__ scid, float4* __restrict__ sbox)
{
  int n = blockIdx.x*256 + threadIdx.x;
  if (n >= NB) return;
  int r = rank[n];
  perm[r] = n;
  scid[r] = cid[n];
  float4 b;
  b.x = det[0*NB + n]; b.y = det[1*NB + n];
  b.z = det[2*NB + n]; b.w = det[3*NB + n];
  sbox[r] = b;
}

// ---------------- k_supmat: pairwise suppression bits for top T_PRE ----------------
// tile (ti,tj) = 64 rows x 64 cols; one wave per tile; lane ii keeps row word.
__global__ __launch_bounds__(256) void k_supmat(const float4* __restrict__ sbox,
    unsigned long long* __restrict__ supmat)
{
  const int lane = threadIdx.x & 63;
  const int wv   = threadIdx.x >> 6;
  const int ti = blockIdx.x;           // 0..15
  const int tj = blockIdx.y*4 + wv;    // 0..15
  float4 bj = sbox[tj*64 + lane];
  float aj = (bj.z - bj.x) * (bj.w - bj.y);
  float4 bi_all = sbox[ti*64 + lane];
  float ai_all  = (bi_all.z - bi_all.x) * (bi_all.w - bi_all.y);
  const int jg = tj*64 + lane;
  unsigned long long myrow = 0ull;
  #pragma unroll 4
  for (int ii = 0; ii < 64; ++ii){
    float bix = __shfl(bi_all.x, ii, 64);
    float biy = __shfl(bi_all.y, ii, 64);
    float biz = __shfl(bi_all.z, ii, 64);
    float biw = __shfl(bi_all.w, ii, 64);
    float ai  = __shfl(ai_all,  ii, 64);
    float ix1 = fmaxf(bix, bj.x), iy1 = fmaxf(biy, bj.y);
    float ix2 = fminf(biz, bj.z), iy2 = fminf(biw, bj.w);
    float inter = fmaxf(ix2 - ix1, 0.f) * fmaxf(iy2 - iy1, 0.f);
    bool sup = (jg > ti*64 + ii) && (inter / (ai + aj - inter) >= IOUT);  // exact ref fp32 expr
    unsigned long long bal = __ballot(sup);
    if (lane == ii) myrow = bal;
  }
  supmat[(size_t)(ti*64 + lane)*TW + tj] = myrow;   // writes ALL words (ws is poisoned)
}

// ---------------- k_greedy: single-wave greedy scan over bit rows ----------------
__global__ __launch_bounds__(64) void k_greedy(const float4* __restrict__ sbox,
    const int* __restrict__ scid, const int* __restrict__ perm,
    const unsigned long long* __restrict__ supmat, const int* __restrict__ nvalid,
    int* __restrict__ selorig, int4* __restrict__ selbox, int* __restrict__ selcid,
    int* __restrict__ nsel)
{
  __shared__ float4 keptbox[KTOP];
  __shared__ int    keptpos[KTOP];
  const int lane = threadIdx.x;
  const int nv = *nvalid;
  // keep-word init: sorted position valid <=> pos < nvalid (finite keys sort first)
  unsigned long long keepw = 0ull;
  if (lane < TW){
    int nbits = nv - lane*64;
    if (nbits >= 64) keepw = ~0ull;
    else if (nbits > 0) keepw = (1ull << nbits) - 1ull;
  }
  int found = 0;
  while (found < KTOP){
    unsigned long long w = keepw;
    int pos = w ? (lane*64 + (int)__builtin_ctzll(w)) : 0x7fffffff;
    #pragma unroll
    for (int s = 32; s > 0; s >>= 1) pos = min(pos, __shfl_xor(pos, s, 64));
    if (pos == 0x7fffffff) break;
    const int i = pos;
    if (lane == 0){ keptbox[found] = sbox[i]; keptpos[found] = i; }
    found++;
    if (lane == (i >> 6)) keepw &= ~(1ull << (i & 63));
    if (found >= KTOP) break;              // 100th kept never needs to suppress
    unsigned long long row = (lane < TW) ? supmat[(size_t)i*TW + lane] : 0ull;
    keepw &= ~row;
  }
  __syncthreads();
  // exact fallback over sorted positions >= T_PRE (never taken on this data)
  for (int j = T_PRE; j < nv && found < KTOP; ++j){
    float4 bj = sbox[j];
    float ajj = (bj.z - bj.x) * (bj.w - bj.y);
    bool supAny = false;
    for (int base = 0; base < found; base += 64){
      int l = base + lane;
      bool s = false;
      if (l < found){
        float4 kb = keptbox[l];
        float ka = (kb.z - kb.x) * (kb.w - kb.y);
        float ix1 = fmaxf(kb.x, bj.x), iy1 = fmaxf(kb.y, bj.y);
        float ix2 = fminf(kb.z, bj.z), iy2 = fminf(kb.w, bj.w);
        float inter = fmaxf(ix2 - ix1, 0.f) * fmaxf(iy2 - iy1, 0.f);
        s = inter / (ka + ajj - inter) >= IOUT;
      }
      if (__ballot(s)) supAny = true;
    }
    if (!supAny){
      if (lane == 0){ keptbox[found] = bj; keptpos[found] = j; }
      found++;
    }
    __syncthreads();
  }
  __syncthreads();
  // output
  for (int base = 0; base < found; base += 64){
    int k = base + lane;
    if (k < found){
      int si = keptpos[k];
      float4 b = keptbox[k];
      selorig[k] = perm[si];
      selbox[k]  = make_int4((int)b.x, (int)b.y, (int)b.z, (int)b.w); // trunc==floor, coords>=0
      selcid[k]  = scid[si];
    }
  }
  if (lane == 0) *nsel = found;
}

// ---------------- k_mask: mask logits (32-dot) -> hard bits ----------------
__global__ __launch_bounds__(256) void k_mask(const float* __restrict__ det, const float* __restrict__ proto,
    const int* __restrict__ selorig, const int* __restrict__ nsel, unsigned int* __restrict__ hb)
{
  const int p    = blockIdx.x*256 + threadIdx.x;          // 0..25599
  const int lane = threadIdx.x & 63;
  const int wword = (blockIdx.x*256 + (threadIdx.x & ~63)) >> 5;  // 2 u32 words per wave
  float pr[NMK];
  #pragma unroll
  for (int m = 0; m < NMK; ++m) pr[m] = proto[m*MP + p];
  const int ns = *nsel;
  const int k0 = blockIdx.y * 10;
  for (int kk = 0; kk < 10; ++kk){
    int k = k0 + kk;
    if (k >= ns) break;                                   // uniform
    int so = selorig[k];
    const float* cf = det + 84*NB + so;                   // uniform -> scalar loads
    float acc = 0.f;
    #pragma unroll
    for (int m = 0; m < NMK; ++m) acc = fmaf(cf[(size_t)m*NB], pr[m], acc);
    unsigned long long bal = __ballot(acc > 0.f);         // hard = sigmoid>0.5 <=> logit>0
    if (lane == 0)  hb[k*800 + wword]     = (unsigned int)bal;
    if (lane == 32) hb[k*800 + wword + 1] = (unsigned int)(bal >> 32);
  }
}

// ---------------- k_paint: winner-per-pixel + coalesced one-hot row writes ----------------
__global__ __launch_bounds__(256) void k_paint(const int4* __restrict__ selbox, const int* __restrict__ selcid,
    const int* __restrict__ nsel, const unsigned int* __restrict__ hb, float* __restrict__ out)
{
  __shared__ int4  sbx[KTOP];
  __shared__ int   scd[KTOP];
  __shared__ short wcls[IW];
  __shared__ short clist[KTOP];
  __shared__ int   ccount;
  const int y = blockIdx.x;
  const int tid = threadIdx.x;
  const int ns = *nsel;
  if (tid < ns){ sbx[tid] = selbox[tid]; scd[tid] = selcid[tid]; }
  if (tid == 0) ccount = 0;
  __syncthreads();
  if (tid == 0){  // boxes intersecting this row, ascending k
    int m = 0;
    for (int k = 0; k < ns; ++k)
      if (y >= sbx[k].y && y < sbx[k].w) clist[m++] = (short)k;
    ccount = m;
  }
  __syncthreads();
  const int m = ccount;
  const int fyi = (y - 2) >> 2;                      // floor((y+0.5)/4 - 0.5)
  const int ylo = max(fyi, 0), yhi = min(fyi + 1, MH_ - 1);
  for (int x = tid; x < IW; x += 256){
    int cls = -1;
    for (int ci = m - 1; ci >= 0; --ci){             // highest k containing pixel wins
      int k = clist[ci];
      int4 b = sbx[k];
      if (x >= b.x && x < b.z){
        int fx = (x - 2) >> 2;
        int xlo = max(fx, 0), xhi = min(fx + 1, MH_ - 1);
        bool on = false;
        for (int ry = ylo; ry <= yhi; ++ry)
          for (int rx = xlo; rx <= xhi; ++rx){
            int pp = ry*MH_ + rx;
            on = on || ((hb[k*800 + (pp >> 5)] >> (pp & 31)) & 1u);
          }
        cls = on ? scd[k] : -1;                      // painted-zero == untouched-zero
        break;
      }
    }
    wcls[x] = (short)cls;
  }
  __syncthreads();
  // write 640*80 floats for this row, float4-coalesced (80 % 4 == 0 -> no pixel crossing)
  float4* o4 = (float4*)(out + (size_t)y * (IW*NCLS));
  for (int it = 0; it < 50; ++it){
    int f4 = it*256 + tid;         // 0..12799
    int x  = f4 / 20;
    int c  = (f4 % 20) * 4;
    int wc = wcls[x];
    float4 v;
    v.x = (wc == c    ) ? 1.f : 0.f;
    v.y = (wc == c + 1) ? 1.f : 0.f;
    v.z = (wc == c + 2) ? 1.f : 0.f;
    v.w = (wc == c + 3) ? 1.f : 0.f;
    o4[f4] = v;
  }
}

extern "C" void kernel_launch(void* const* d_in, const int* in_sizes, int n_in,
                              void* d_out, int out_size, void* d_ws, size_t ws_size,
                              hipStream_t stream)
{
  const float* det   = (const float*)d_in[0];   // (1,116,8400)
  const float* proto = (const float*)d_in[1];   // (1,32,160,160)
  float* out = (float*)d_out;                   // (1,640,640,80)
  char* w = (char*)d_ws;
  float*  key     = (float*)(w + 0);            // 33600
  int*    cid     = (int*)  (w + 33600);        // 33600
  int*    rank    = (int*)  (w + 67200);        // 33600
  int*    perm    = (int*)  (w + 100800);       // 33600
  int*    scid    = (int*)  (w + 134400);       // 33600
  float4* sbox    = (float4*)(w + 168000);      // 134400, 16B aligned
  int*    selorig = (int*)  (w + 302400);       // 400
  int4*   selbox  = (int4*) (w + 302800);       // 1600, 16B aligned
  int*    selcid  = (int*)  (w + 304400);       // 400
  int*    nsel    = (int*)  (w + 304800);       // 4
  int*    nvalid  = (int*)  (w + 304804);       // 4
  unsigned int* hb = (unsigned int*)(w + 304816);              // 320000
  unsigned long long* supmat = (unsigned long long*)(w + 304816); // aliases hb (131072 B, done before k_mask)

  hipMemsetAsync(nvalid, 0, 4, stream);
  hipLaunchKernelGGL(k_prep,    dim3(33),      dim3(256), 0, stream, det, key, cid, rank, nvalid);
  hipLaunchKernelGGL(k_rank,    dim3(33, 8),   dim3(256), 0, stream, key, rank);
  hipLaunchKernelGGL(k_scatter, dim3(33),      dim3(256), 0, stream, det, cid, rank, perm, scid, sbox);
  hipLaunchKernelGGL(k_supmat,  dim3(16, 4),   dim3(256), 0, stream, sbox, supmat);
  hipLaunchKernelGGL(k_greedy,  dim3(1),       dim3(64),  0, stream, sbox, scid, perm, supmat, nvalid,
                     selorig, selbox, selcid, nsel);
  hipLaunchKernelGGL(k_mask,    dim3(100, 10), dim3(256), 0, stream, det, proto, selorig, nsel, hb);
  hipLaunchKernelGGL(k_paint,   dim3(640),     dim3(256), 0, stream, selbox, selcid, nsel, hb, out);
}

// Round 3
// 250.586 us; speedup vs baseline: 1.6437x; 1.1721x over previous
//
#include <hip/hip_runtime.h>

#define NCLS 80
#define NMK  32
#define NB   8400
#define MH_  160
#define MP   25600     // 160*160
#define IH   640
#define IW   640
#define KTOP 100
#define CONFT 0.4f
#define IOUT 0.7f
#define T_PRE 960      // NMS prefix handled by bit-matrix (15 tiles of 64)
#define TW   (T_PRE/64)  // 15 u64 words per row

// ---------------- k_prep: score/argmax/key + nvalid count ----------------
__global__ __launch_bounds__(256) void k_prep(const float* __restrict__ det,
    float* __restrict__ key, int* __restrict__ cid, int* __restrict__ rank,
    int* __restrict__ nvalid)
{
  int n = blockIdx.x*256 + threadIdx.x;
  if (n >= NB) return;
  float best = det[4*NB + n];
  int bc = 0;
  #pragma unroll 8
  for (int c = 1; c < NCLS; ++c){
    float v = det[(4+c)*NB + n];
    if (v > best){ best = v; bc = c; }   // strict > keeps FIRST max (matches jnp.argmax)
  }
  cid[n] = bc;
  bool valid = best >= CONFT;
  key[n] = valid ? -best : __builtin_inff();  // ascending argsort key; inf sorts last
  rank[n] = 0;
  unsigned long long bal = __ballot(valid);
  if ((threadIdx.x & 63) == 0) atomicAdd(nvalid, (int)__popcll(bal));
}

// ---------------- k_rank: O(N^2) stable rank, j-sliced 8 ways ----------------
__global__ __launch_bounds__(256) void k_rank(const float* __restrict__ key, int* __restrict__ rank)
{
  __shared__ float tk[256];
  int n = blockIdx.x*256 + threadIdx.x;
  float kn = (n < NB) ? key[n] : 0.f;
  int j0 = blockIdx.y * 1050;          // 8 * 1050 == 8400
  int j1 = j0 + 1050;
  int part = 0;
  for (int t0 = j0; t0 < j1; t0 += 256){
    int j = t0 + threadIdx.x;
    tk[threadIdx.x] = (j < NB) ? key[j] : 0.f;
    __syncthreads();
    int lim = min(256, j1 - t0);
    for (int jj = 0; jj < lim; ++jj){
      float kj = tk[jj];
      int jg = t0 + jj;
      part += ((kj < kn) || (kj == kn && jg < n)) ? 1 : 0;  // stable: ties by index
    }
    __syncthreads();
  }
  if (n < NB && part) atomicAdd(&rank[n], part);
}

// ---------------- k_scatter: build sorted arrays ----------------
__global__ __launch_bounds__(256) void k_scatter(const float* __restrict__ det,
    const int* __restrict__ cid, const int* __restrict__ rank,
    int* __restrict__ perm, int* __restrict__ scid, float4* __restrict__ sbox)
{
  int n = blockIdx.x*256 + threadIdx.x;
  if (n >= NB) return;
  int r = rank[n];
  perm[r] = n;
  scid[r] = cid[n];
  float4 b;
  b.x = det[0*NB + n]; b.y = det[1*NB + n];
  b.z = det[2*NB + n]; b.w = det[3*NB + n];
  sbox[r] = b;
}

// ---------------- k_supmat: pairwise suppression bits for top T_PRE ----------------
// one wave per 64x64 tile (ti,tj); lane ii keeps row word via ballot.
__global__ __launch_bounds__(64) void k_supmat(const float4* __restrict__ sbox,
    unsigned long long* __restrict__ supmat)
{
  const int lane = threadIdx.x;
  const int ti = blockIdx.x;           // 0..14
  const int tj = blockIdx.y;           // 0..14
  float4 bj = sbox[tj*64 + lane];
  float aj = (bj.z - bj.x) * (bj.w - bj.y);
  float4 bi_all = sbox[ti*64 + lane];
  float ai_all  = (bi_all.z - bi_all.x) * (bi_all.w - bi_all.y);
  const int jg = tj*64 + lane;
  unsigned long long myrow = 0ull;
  #pragma unroll 4
  for (int ii = 0; ii < 64; ++ii){
    float bix = __shfl(bi_all.x, ii, 64);
    float biy = __shfl(bi_all.y, ii, 64);
    float biz = __shfl(bi_all.z, ii, 64);
    float biw = __shfl(bi_all.w, ii, 64);
    float ai  = __shfl(ai_all,  ii, 64);
    float ix1 = fmaxf(bix, bj.x), iy1 = fmaxf(biy, bj.y);
    float ix2 = fminf(biz, bj.z), iy2 = fminf(biw, bj.w);
    float inter = fmaxf(ix2 - ix1, 0.f) * fmaxf(iy2 - iy1, 0.f);
    bool sup = (jg > ti*64 + ii) && (inter / (ai + aj - inter) >= IOUT);  // exact ref fp32 expr
    unsigned long long bal = __ballot(sup);
    if (lane == ii) myrow = bal;
  }
  supmat[(size_t)(ti*64 + lane)*TW + tj] = myrow;
}

__device__ __forceinline__ unsigned long long shfl64(unsigned long long v, int src){
  int lo = __shfl((int)(unsigned)(v & 0xffffffffull), src, 64);
  int hi = __shfl((int)(unsigned)(v >> 32), src, 64);
  return ((unsigned long long)(unsigned)hi << 32) | (unsigned)lo;
}

// ---------------- k_greedy: copy supmat to LDS, single-wave greedy scan ----------------
__global__ __launch_bounds__(1024) void k_greedy(const float4* __restrict__ sbox,
    const int* __restrict__ scid, const int* __restrict__ perm,
    const unsigned long long* __restrict__ supmat, const int* __restrict__ nvalid,
    int* __restrict__ selorig, int4* __restrict__ selbox, int* __restrict__ selcid,
    int* __restrict__ nsel)
{
  __shared__ __align__(16) unsigned long long lsup[T_PRE*TW];  // 112.5 KB
  __shared__ int keptpos[KTOP];
  __shared__ int s_found;
  const int tid = threadIdx.x;
  // cooperative copy: 960*15 u64 = 7200 float4
  {
    const float4* g4 = (const float4*)supmat;
    float4* l4 = (float4*)lsup;
    for (int idx = tid; idx < (T_PRE*TW)/2; idx += 1024) l4[idx] = g4[idx];
  }
  __syncthreads();

  if (tid < 64){
    const int lane = tid;
    const int nv = *nvalid;
    // keep-word init: sorted position valid <=> pos < nvalid (finite keys sort first)
    unsigned long long keepw = 0ull;
    if (lane < TW){
      int nbits = nv - lane*64;
      if (nbits >= 64) keepw = ~0ull;
      else if (nbits > 0) keepw = (1ull << nbits) - 1ull;
    }
    int found = 0;
    int cw = 0;
    for (;;){
      // find next set bit: current word usually nonzero (suppression rare)
      int pos = -1;
      for (;;){
        unsigned long long w = shfl64(keepw, cw);
        if (w){ pos = (cw << 6) + (int)__builtin_ctzll(w); break; }
        if (++cw == TW) break;
      }
      if (pos < 0) break;
      if (lane == 0) keptpos[found] = pos;
      found++;
      if (found >= KTOP) break;             // 100th kept never needs to suppress
      if (lane == cw) keepw &= ~(1ull << (pos & 63));
      if (lane < TW) keepw &= ~lsup[pos*TW + lane];
    }
    // exact fallback over sorted positions >= T_PRE (never taken on this data)
    if (found < KTOP && nv > T_PRE){
      float4 kbA = make_float4(0.f,0.f,0.f,0.f);
      float4 kbB = make_float4(0.f,0.f,0.f,0.f);
      if (lane < found)      kbA = sbox[keptpos[lane]];
      if (lane + 64 < found) kbB = sbox[keptpos[lane + 64]];
      for (int j = T_PRE; j < nv && found < KTOP; ++j){
        float4 bj = sbox[j];
        float ajj = (bj.z - bj.x) * (bj.w - bj.y);
        bool s = false;
        if (lane < found){
          float ka = (kbA.z - kbA.x) * (kbA.w - kbA.y);
          float ix1 = fmaxf(kbA.x, bj.x), iy1 = fmaxf(kbA.y, bj.y);
          float ix2 = fminf(kbA.z, bj.z), iy2 = fminf(kbA.w, bj.w);
          float inter = fmaxf(ix2 - ix1, 0.f) * fmaxf(iy2 - iy1, 0.f);
          s = inter / (ka + ajj - inter) >= IOUT;
        }
        if (lane + 64 < found){
          float ka = (kbB.z - kbB.x) * (kbB.w - kbB.y);
          float ix1 = fmaxf(kbB.x, bj.x), iy1 = fmaxf(kbB.y, bj.y);
          float ix2 = fminf(kbB.z, bj.z), iy2 = fminf(kbB.w, bj.w);
          float inter = fmaxf(ix2 - ix1, 0.f) * fmaxf(iy2 - iy1, 0.f);
          s = s || (inter / (ka + ajj - inter) >= IOUT);
        }
        if (!__ballot(s)){
          if (lane == 0) keptpos[found] = j;
          if (found < 64){ if (lane == found) kbA = bj; }
          else           { if (lane == found - 64) kbB = bj; }
          found++;
        }
      }
    }
    if (lane == 0) s_found = found;
  }
  __syncthreads();
  const int ns = s_found;
  if (tid < ns){
    int si = keptpos[tid];
    float4 b = sbox[si];
    selorig[tid] = perm[si];
    selbox[tid]  = make_int4((int)b.x, (int)b.y, (int)b.z, (int)b.w); // trunc==floor, coords>=0
    selcid[tid]  = scid[si];
  }
  if (tid == 0) *nsel = ns;
}

// ---------------- k_mask: mask logits (32-dot) -> hard bits ----------------
__global__ __launch_bounds__(256) void k_mask(const float* __restrict__ det, const float* __restrict__ proto,
    const int* __restrict__ selorig, const int* __restrict__ nsel, unsigned int* __restrict__ hb)
{
  const int p    = blockIdx.x*256 + threadIdx.x;          // 0..25599
  const int lane = threadIdx.x & 63;
  const int wword = (blockIdx.x*256 + (threadIdx.x & ~63)) >> 5;  // 2 u32 words per wave
  float pr[NMK];
  #pragma unroll
  for (int m = 0; m < NMK; ++m) pr[m] = proto[m*MP + p];
  const int ns = *nsel;
  const int k0 = blockIdx.y * 10;
  for (int kk = 0; kk < 10; ++kk){
    int k = k0 + kk;
    if (k >= ns) break;                                   // uniform
    int so = selorig[k];
    const float* cf = det + 84*NB + so;                   // uniform -> scalar loads
    float acc = 0.f;
    #pragma unroll
    for (int m = 0; m < NMK; ++m) acc = fmaf(cf[(size_t)m*NB], pr[m], acc);
    unsigned long long bal = __ballot(acc > 0.f);         // hard = sigmoid>0.5 <=> logit>0
    if (lane == 0)  hb[k*800 + wword]     = (unsigned int)bal;
    if (lane == 32) hb[k*800 + wword + 1] = (unsigned int)(bal >> 32);
  }
}

// ---------------- k_paint: winner-per-pixel + coalesced one-hot row writes ----------------
__global__ __launch_bounds__(256) void k_paint(const int4* __restrict__ selbox, const int* __restrict__ selcid,
    const int* __restrict__ nsel, const unsigned int* __restrict__ hb, float* __restrict__ out)
{
  __shared__ int4  sbx[KTOP];
  __shared__ int   scd[KTOP];
  __shared__ short wcls[IW];
  __shared__ short clist[KTOP];
  __shared__ int   ccount;
  const int y = blockIdx.x;
  const int tid = threadIdx.x;
  const int ns = *nsel;
  if (tid < ns){ sbx[tid] = selbox[tid]; scd[tid] = selcid[tid]; }
  if (tid == 0) ccount = 0;
  __syncthreads();
  if (tid == 0){  // boxes intersecting this row, ascending k
    int m = 0;
    for (int k = 0; k < ns; ++k)
      if (y >= sbx[k].y && y < sbx[k].w) clist[m++] = (short)k;
    ccount = m;
  }
  __syncthreads();
  const int m = ccount;
  const int fyi = (y - 2) >> 2;                      // floor((y+0.5)/4 - 0.5)
  const int ylo = max(fyi, 0), yhi = min(fyi + 1, MH_ - 1);
  for (int x = tid; x < IW; x += 256){
    int cls = -1;
    for (int ci = m - 1; ci >= 0; --ci){             // highest k containing pixel wins
      int k = clist[ci];
      int4 b = sbx[k];
      if (x >= b.x && x < b.z){
        int fx = (x - 2) >> 2;
        int xlo = max(fx, 0), xhi = min(fx + 1, MH_ - 1);
        bool on = false;
        for (int ry = ylo; ry <= yhi; ++ry)
          for (int rx = xlo; rx <= xhi; ++rx){
            int pp = ry*MH_ + rx;
            on = on || ((hb[k*800 + (pp >> 5)] >> (pp & 31)) & 1u);
          }
        cls = on ? scd[k] : -1;                      // painted-zero == untouched-zero
        break;
      }
    }
    wcls[x] = (short)cls;
  }
  __syncthreads();
  // write 640*80 floats for this row, float4-coalesced (80 % 4 == 0 -> no pixel crossing)
  float4* o4 = (float4*)(out + (size_t)y * (IW*NCLS));
  for (int it = 0; it < 50; ++it){
    int f4 = it*256 + tid;         // 0..12799
    int x  = f4 / 20;
    int c  = (f4 % 20) * 4;
    int wc = wcls[x];
    float4 v;
    v.x = (wc == c    ) ? 1.f : 0.f;
    v.y = (wc == c + 1) ? 1.f : 0.f;
    v.z = (wc == c + 2) ? 1.f : 0.f;
    v.w = (wc == c + 3) ? 1.f : 0.f;
    o4[f4] = v;
  }
}

extern "C" void kernel_launch(void* const* d_in, const int* in_sizes, int n_in,
                              void* d_out, int out_size, void* d_ws, size_t ws_size,
                              hipStream_t stream)
{
  const float* det   = (const float*)d_in[0];   // (1,116,8400)
  const float* proto = (const float*)d_in[1];   // (1,32,160,160)
  float* out = (float*)d_out;                   // (1,640,640,80)
  char* w = (char*)d_ws;
  float*  key     = (float*)(w + 0);            // 33600
  int*    cid     = (int*)  (w + 33600);        // 33600
  int*    rank    = (int*)  (w + 67200);        // 33600
  int*    perm    = (int*)  (w + 100800);       // 33600
  int*    scid    = (int*)  (w + 134400);       // 33600
  float4* sbox    = (float4*)(w + 168000);      // 134400, 16B aligned
  int*    selorig = (int*)  (w + 302400);       // 400
  int4*   selbox  = (int4*) (w + 302800);       // 1600, 16B aligned
  int*    selcid  = (int*)  (w + 304400);       // 400
  int*    nsel    = (int*)  (w + 304800);       // 4
  int*    nvalid  = (int*)  (w + 304804);       // 4
  unsigned int* hb = (unsigned int*)(w + 304816);              // 320000
  unsigned long long* supmat = (unsigned long long*)(w + 304816); // aliases hb (115200 B, done before k_mask)

  hipMemsetAsync(nvalid, 0, 4, stream);
  hipLaunchKernelGGL(k_prep,    dim3(33),      dim3(256),  0, stream, det, key, cid, rank, nvalid);
  hipLaunchKernelGGL(k_rank,    dim3(33, 8),   dim3(256),  0, stream, key, rank);
  hipLaunchKernelGGL(k_scatter, dim3(33),      dim3(256),  0, stream, det, cid, rank, perm, scid, sbox);
  hipLaunchKernelGGL(k_supmat,  dim3(15, 15),  dim3(64),   0, stream, sbox, supmat);
  hipLaunchKernelGGL(k_greedy,  dim3(1),       dim3(1024), 0, stream, sbox, scid, perm, supmat, nvalid,
                     selorig, selbox, selcid, nsel);
  hipLaunchKernelGGL(k_mask,    dim3(100, 10), dim3(256),  0, stream, det, proto, selorig, nsel, hb);
  hipLaunchKernelGGL(k_paint,   dim3(640),     dim3(256),  0, stream, selbox, selcid, nsel, hb, out);
}